// Round 9
// baseline (631.115 us; speedup 1.0000x reference)
//
#include <hip/hip_runtime.h>
#include <hip/hip_bf16.h>

#define S_LEN 2048
#define DM 1024
#define NH 16
#define DH 64
#define MTOK 4096

typedef __attribute__((ext_vector_type(8))) __bf16 bf16x8;
typedef __attribute__((ext_vector_type(4))) float f32x4;
typedef __attribute__((ext_vector_type(16))) float f32x16;
typedef unsigned short u16;
typedef unsigned long long u64;

__device__ __forceinline__ u16 f2bf(float f) {
  union { float f; unsigned u; } a; a.f = f;
  unsigned u = a.u;
  u += 0x7fffu + ((u >> 16) & 1u);   // RNE
  return (u16)(u >> 16);
}

__device__ __forceinline__ bf16x8 ld_bf8(const u16* p) {
  return *reinterpret_cast<const bf16x8*>(p);
}

// ---------------- fp32 -> bf16 convert ----------------
__global__ void k_convert(const float* __restrict__ src, u16* __restrict__ dst, int n4) {
  int i = blockIdx.x * blockDim.x + threadIdx.x;
  int stride = gridDim.x * blockDim.x;
  for (; i < n4; i += stride) {
    float4 v = reinterpret_cast<const float4*>(src)[i];
    ushort4 o;
    o.x = f2bf(v.x); o.y = f2bf(v.y); o.z = f2bf(v.z); o.w = f2bf(v.w);
    reinterpret_cast<ushort4*>(dst)[i] = o;
  }
}

// ---------------- mask bit-pack: [B][S][S] i32 -> [B][S][S/64] u64 ----------------
__global__ void k_maskpack(const int* __restrict__ m, u64* __restrict__ o, int n) {
  int i = blockIdx.x * blockDim.x + threadIdx.x;
  int stride = gridDim.x * blockDim.x;
  for (; i < n; i += stride) {
    u64 bal = __ballot(m[i] != 0);
    if ((i & 63) == 0) o[i >> 6] = bal;
  }
}

// ---------------- bf16 GEMM, B^T weights: C = A @ W^T + bias ----------------
template<int MODE>
__global__ __launch_bounds__(256) void k_gemm(
    const u16* __restrict__ A, const u16* __restrict__ Bw,
    const float* __restrict__ bias, void* __restrict__ dst) {
  constexpr int K = DM;
  __shared__ u16 As[128 * 32];
  __shared__ u16 Bs[128 * 32];
  const int tid = threadIdx.x;
  const int lane = tid & 63;
  const int wid = tid >> 6;
  const int wm = wid >> 1, wn = wid & 1;
  const int bm = blockIdx.x * 128;
  const int bn = blockIdx.y * 128;
  const int r0 = tid >> 2;
  const int c0 = (tid & 3) * 8;
  const int fr = lane & 15;
  const int fk = (lane >> 4) * 8;

  f32x4 acc[4][4] = {};

  const u16* ga = A + (size_t)(bm + r0) * K + c0;
  const u16* gb = Bw + (size_t)(bn + r0) * K + c0;

  for (int kt = 0; kt < K; kt += 32) {
    __syncthreads();
    __builtin_amdgcn_global_load_lds(
        (const __attribute__((address_space(1))) void*)(ga + kt),
        (__attribute__((address_space(3))) void*)(&As[r0 * 32 + c0]), 16, 0, 0);
    __builtin_amdgcn_global_load_lds(
        (const __attribute__((address_space(1))) void*)(ga + (size_t)64 * K + kt),
        (__attribute__((address_space(3))) void*)(&As[(r0 + 64) * 32 + c0]), 16, 0, 0);
    __builtin_amdgcn_global_load_lds(
        (const __attribute__((address_space(1))) void*)(gb + kt),
        (__attribute__((address_space(3))) void*)(&Bs[r0 * 32 + c0]), 16, 0, 0);
    __builtin_amdgcn_global_load_lds(
        (const __attribute__((address_space(1))) void*)(gb + (size_t)64 * K + kt),
        (__attribute__((address_space(3))) void*)(&Bs[(r0 + 64) * 32 + c0]), 16, 0, 0);
    __syncthreads();
    bf16x8 af[4], bfr[4];
#pragma unroll
    for (int m = 0; m < 4; ++m) af[m] = ld_bf8(&As[(wm * 64 + m * 16 + fr) * 32 + fk]);
#pragma unroll
    for (int n = 0; n < 4; ++n) bfr[n] = ld_bf8(&Bs[(wn * 64 + n * 16 + fr) * 32 + fk]);
#pragma unroll
    for (int m = 0; m < 4; ++m)
#pragma unroll
      for (int n = 0; n < 4; ++n)
        acc[m][n] = __builtin_amdgcn_mfma_f32_16x16x32_bf16(af[m], bfr[n], acc[m][n], 0, 0, 0);
  }

  const int cr = (lane >> 4) * 4;
  const int cc = lane & 15;
#pragma unroll
  for (int m = 0; m < 4; ++m) {
#pragma unroll
    for (int n = 0; n < 4; ++n) {
      const int colg = bn + wn * 64 + n * 16 + cc;
      const float bv = bias[colg];
      const int rbase = bm + wm * 64 + m * 16 + cr;
      if (MODE == 2) {
        float* o = (float*)dst;
#pragma unroll
        for (int r = 0; r < 4; ++r)
          o[(size_t)(rbase + r) * DM + colg] = acc[m][n][r] + bv;
      } else if (MODE == 0) {
        u16* o = (u16*)dst;
        const int h = colg >> 6, d = colg & 63;
#pragma unroll
        for (int r = 0; r < 4; ++r) {
          const int tok = rbase + r;
          const int b = tok >> 11, s = tok & 2047;
          o[(((size_t)(b * NH + h) * S_LEN) + s) * DH + d] = f2bf(acc[m][n][r] + bv);
        }
      } else {
        u16* o = (u16*)dst;
        const int h = colg >> 6, d = colg & 63;
        const int tok = rbase;
        const int b = tok >> 11, s = tok & 2047;
        ushort4 pk;
        pk.x = f2bf(acc[m][n][0] + bv);
        pk.y = f2bf(acc[m][n][1] + bv);
        pk.z = f2bf(acc[m][n][2] + bv);
        pk.w = f2bf(acc[m][n][3] + bv);
        *reinterpret_cast<ushort4*>(&o[(((size_t)(b * NH + h) * DH) + d) * S_LEN + s]) = pk;
      }
    }
  }
}

// ---------------- fused flash attention ----------------
// Block = 4 waves x 32 q-rows = 128 q, ONE batch (b = blockIdx.z).
// LDS halved to 32 KB -> 4 blocks/CU -> 4 waves/SIMD (vs 2 in R8).
// Counted-vmcnt barrier (T4), setprio (T5), bias/mask 2-stage reg prefetch,
// XOR-swizzled K/V via pre-swizzled gload_lds source, swapped 32x32x16 QK^T,
// in-register softmax (tree-ified), P repack via shfl_xor(32), PV from LDS V^T.
__global__ __launch_bounds__(256, 4) void k_attn(
    const u16* __restrict__ Qb, const u16* __restrict__ Kb, const u16* __restrict__ Vt,
    const float* __restrict__ bias, const u64* __restrict__ mpk,
    u16* __restrict__ ctx) {
  __shared__ u16 lds[2][2][4096];   // [buf][K, V][64*64]
  const int tid = threadIdx.x;
  const int lane = tid & 63;
  const int w = tid >> 6;
  const int b = blockIdx.z;
  const int h = blockIdx.y;
  const int q0 = blockIdx.x * 128 + w * 32;
  const int lq = lane & 31;
  const int hi = lane >> 5;

  const float* bp = bias + (size_t)h * S_LEN * S_LEN;
  const u16* Kp = Kb + (size_t)(b * NH + h) * S_LEN * DH;
  const u16* Vp = Vt + (size_t)(b * NH + h) * DH * S_LEN;

  bf16x8 qf[4];
  f32x16 cacc[2] = {};
  float m_run = -1e30f, l_run = 0.f;
  {
    const u16* Qp = Qb + (size_t)(b * NH + h) * S_LEN * DH;
#pragma unroll
    for (int d0 = 0; d0 < 4; ++d0)
      qf[d0] = ld_bf8(&Qp[(size_t)(q0 + lq) * DH + d0 * 16 + hi * 8]);
  }

#define STAGE(ktv, cb) {                                                          \
    _Pragma("unroll") for (int i = 0; i < 2; ++i) {                               \
      const int el = (i * 256 + tid) * 8;                                         \
      const int rr = el >> 6;                                                     \
      const int ce = ((tid & 7) * 8) ^ ((rr & 7) << 3);                           \
      const u16* ksrc = Kp + (size_t)((ktv) + rr) * DH + ce;                      \
      const u16* vsrc = Vp + (size_t)rr * S_LEN + (ktv) + ce;                     \
      __builtin_amdgcn_global_load_lds(                                           \
          (const __attribute__((address_space(1))) void*)ksrc,                    \
          (__attribute__((address_space(3))) void*)&lds[cb][0][el], 16, 0, 0);    \
      __builtin_amdgcn_global_load_lds(                                           \
          (const __attribute__((address_space(1))) void*)vsrc,                    \
          (__attribute__((address_space(3))) void*)&lds[cb][1][el], 16, 0, 0);    \
    } }

#define LDSREAD(cb, tile, row, cel) \
    ld_bf8(&lds[cb][tile][(row) * 64 + (((cel)) ^ (((row) & 7) << 3))])

#define LOADB(BV, ktv) {                                                          \
    _Pragma("unroll") for (int kb = 0; kb < 2; ++kb)                              \
      _Pragma("unroll") for (int rq = 0; rq < 4; ++rq)                            \
        BV[kb][rq] = *reinterpret_cast<const float4*>(                            \
            &bp[(size_t)(q0 + lq) * S_LEN + (ktv) + kb * 32 + rq * 8 + hi * 4]); }

// counted-vmcnt barrier: drain 4 stage loads (oldest), keep 9 bias/mask in flight
#define BARRIER() {                                                               \
    asm volatile("s_waitcnt vmcnt(9) lgkmcnt(0)" ::: "memory");                   \
    __builtin_amdgcn_sched_barrier(0);                                            \
    __builtin_amdgcn_s_barrier();                                                 \
    __builtin_amdgcn_sched_barrier(0); }

#define BODY(T, BV, MW, BVN, MWN) {                                               \
    const int ktv = (T) * 64;                                                     \
    BARRIER();                                                                    \
    if ((T) + 1 < S_LEN / 64) {                                                   \
      STAGE(ktv + 64, c ^ 1);                                                     \
      __builtin_amdgcn_sched_barrier(0);                                          \
      LOADB(BVN, ktv + 64);                                                       \
      MWN = mpk[((size_t)(b * S_LEN + q0 + lq)) * 32 + (ktv >> 6) + 1];           \
    }                                                                             \
    f32x16 sc0 = {}, sc1 = {};                                                    \
    __builtin_amdgcn_s_setprio(1);                                                \
    _Pragma("unroll") for (int d0 = 0; d0 < 4; ++d0) {                            \
      bf16x8 ka0 = LDSREAD(c, 0, lq, d0 * 16 + hi * 8);                           \
      sc0 = __builtin_amdgcn_mfma_f32_32x32x16_bf16(ka0, qf[d0], sc0, 0, 0, 0);   \
      bf16x8 ka1 = LDSREAD(c, 0, 32 + lq, d0 * 16 + hi * 8);                      \
      sc1 = __builtin_amdgcn_mfma_f32_32x32x16_bf16(ka1, qf[d0], sc1, 0, 0, 0);   \
    }                                                                             \
    __builtin_amdgcn_s_setprio(0);                                                \
    _Pragma("unroll") for (int r = 0; r < 16; ++r) {                              \
      const int cr_ = (r & 3) + 8 * (r >> 2);                                     \
      const float v0_ = sc0[r] * 0.125f + ((const float*)&BV[0][r >> 2])[r & 3];  \
      sc0[r] = ((MW >> (cr_ + 4 * hi)) & 1) ? v0_ : -1e9f;                        \
      const float v1_ = sc1[r] * 0.125f + ((const float*)&BV[1][r >> 2])[r & 3];  \
      sc1[r] = ((MW >> (32 + cr_ + 4 * hi)) & 1) ? v1_ : -1e9f;                   \
    }                                                                             \
    float mt[16];                                                                 \
    _Pragma("unroll") for (int r = 0; r < 16; ++r) mt[r] = fmaxf(sc0[r], sc1[r]); \
    _Pragma("unroll") for (int r = 0; r < 8; ++r) mt[r] = fmaxf(mt[r], mt[r + 8]);\
    _Pragma("unroll") for (int r = 0; r < 4; ++r) mt[r] = fmaxf(mt[r], mt[r + 4]);\
    float vm = fmaxf(fmaxf(mt[0], mt[1]), fmaxf(mt[2], mt[3]));                   \
    vm = fmaxf(vm, __shfl_xor(vm, 32));                                           \
    if (!__all(vm <= m_run)) {                                                    \
      const float mn = fmaxf(m_run, vm);                                          \
      const float corr = __expf(m_run - mn);                                      \
      m_run = mn;                                                                 \
      l_run *= corr;                                                              \
      _Pragma("unroll") for (int r = 0; r < 16; ++r) {                            \
        cacc[0][r] *= corr; cacc[1][r] *= corr; }                                 \
    }                                                                             \
    float st[16];                                                                 \
    _Pragma("unroll") for (int r = 0; r < 16; ++r) {                              \
      const float p0 = __expf(sc0[r] - m_run); sc0[r] = p0;                       \
      const float p1 = __expf(sc1[r] - m_run); sc1[r] = p1;                       \
      st[r] = p0 + p1;                                                            \
    }                                                                             \
    _Pragma("unroll") for (int r = 0; r < 8; ++r) st[r] += st[r + 8];             \
    _Pragma("unroll") for (int r = 0; r < 4; ++r) st[r] += st[r + 4];             \
    float ssum = (st[0] + st[1]) + (st[2] + st[3]);                               \
    ssum += __shfl_xor(ssum, 32);                                                 \
    l_run += ssum;                                                                \
    unsigned pw0[8], pw1[8];                                                      \
    _Pragma("unroll") for (int i2 = 0; i2 < 8; ++i2) {                            \
      pw0[i2] = (unsigned)f2bf(sc0[2 * i2]) | ((unsigned)f2bf(sc0[2 * i2 + 1]) << 16); \
      pw1[i2] = (unsigned)f2bf(sc1[2 * i2]) | ((unsigned)f2bf(sc1[2 * i2 + 1]) << 16); \
    }                                                                             \
    bf16x8 pf[4];                                                                 \
    _Pragma("unroll") for (int kb = 0; kb < 2; ++kb)                              \
      _Pragma("unroll") for (int ch = 0; ch < 2; ++ch) {                          \
        const unsigned a0 = kb ? pw1[ch * 4 + 0] : pw0[ch * 4 + 0];               \
        const unsigned a1 = kb ? pw1[ch * 4 + 1] : pw0[ch * 4 + 1];               \
        const unsigned a2 = kb ? pw1[ch * 4 + 2] : pw0[ch * 4 + 2];               \
        const unsigned a3 = kb ? pw1[ch * 4 + 3] : pw0[ch * 4 + 3];               \
        const unsigned sx0 = __shfl_xor(a0, 32), sx1 = __shfl_xor(a1, 32);        \
        const unsigned sx2 = __shfl_xor(a2, 32), sx3 = __shfl_xor(a3, 32);        \
        union { unsigned u[4]; bf16x8 v; } f;                                     \
        f.u[0] = hi ? sx2 : a0;                                                   \
        f.u[1] = hi ? sx3 : a1;                                                   \
        f.u[2] = hi ? a2 : sx0;                                                   \
        f.u[3] = hi ? a3 : sx1;                                                   \
        pf[kb * 2 + ch] = f.v;                                                    \
      }                                                                           \
    __builtin_amdgcn_s_setprio(1);                                                \
    _Pragma("unroll") for (int db = 0; db < 2; ++db)                              \
      _Pragma("unroll") for (int kc = 0; kc < 4; ++kc) {                          \
        bf16x8 va = LDSREAD(c, 1, db * 32 + lq, kc * 16 + hi * 8);                \
        cacc[db] = __builtin_amdgcn_mfma_f32_32x32x16_bf16(va, pf[kc], cacc[db], 0, 0, 0); \
      }                                                                           \
    __builtin_amdgcn_s_setprio(0);                                                \
    c ^= 1;                                                                       \
  }

  float4 bvA[2][4], bvB[2][4];
  u64 mwA, mwB;
  STAGE(0, 0);
  __builtin_amdgcn_sched_barrier(0);
  LOADB(bvA, 0);
  mwA = mpk[((size_t)(b * S_LEN + q0 + lq)) * 32];
  int c = 0;
  for (int t0 = 0; t0 < S_LEN / 64; t0 += 2) {
    BODY(t0, bvA, mwA, bvB, mwB);
    BODY(t0 + 1, bvB, mwB, bvA, mwA);
  }
#undef STAGE
#undef LDSREAD
#undef LOADB
#undef BARRIER
#undef BODY

  // ---- epilogue ----
  {
    const float linv = 1.0f / l_run;
    u16* cp = ctx + ((size_t)(b * S_LEN + q0 + lq)) * DM + h * DH;
#pragma unroll
    for (int db = 0; db < 2; ++db)
#pragma unroll
      for (int r = 0; r < 16; ++r)
        cp[db * 32 + (r & 3) + 8 * (r >> 2) + 4 * hi] = f2bf(cacc[db][r] * linv);
  }
}

extern "C" void kernel_launch(void* const* d_in, const int* in_sizes, int n_in,
                              void* d_out, int out_size, void* d_ws, size_t ws_size,
                              hipStream_t stream) {
  const float* q   = (const float*)d_in[0];
  const float* k   = (const float*)d_in[1];
  const float* v   = (const float*)d_in[2];
  const int*   msk = (const int*)d_in[3];
  const float* pb  = (const float*)d_in[4];
  const float* w_q = (const float*)d_in[5];
  const float* b_q = (const float*)d_in[6];
  const float* w_k = (const float*)d_in[7];
  const float* b_k = (const float*)d_in[8];
  const float* w_v = (const float*)d_in[9];
  const float* b_v = (const float*)d_in[10];
  const float* w_o = (const float*)d_in[11];
  const float* b_o = (const float*)d_in[12];
  float* out = (float*)d_out;

  char* ws = (char*)d_ws;
  u16* wq_bf = (u16*)(ws + ((size_t)0 << 20));
  u16* wk_bf = (u16*)(ws + ((size_t)2 << 20));
  u16* wv_bf = (u16*)(ws + ((size_t)4 << 20));
  u16* wo_bf = (u16*)(ws + ((size_t)6 << 20));
  u16* x_bf  = (u16*)(ws + ((size_t)8 << 20));   // staging; reused as ctx
  u16* Qb    = (u16*)(ws + ((size_t)16 << 20));
  u16* Kb    = (u16*)(ws + ((size_t)24 << 20));
  u16* Vtb   = (u16*)(ws + ((size_t)32 << 20));
  u64* mpk   = (u64*)(ws + ((size_t)40 << 20));  // 1 MB packed mask

  dim3 blk(256);
  const int n4w = DM * DM / 4;
  const int n4x = MTOK * DM / 4;
  k_convert<<<dim3(1024), blk, 0, stream>>>(w_q, wq_bf, n4w);
  k_convert<<<dim3(1024), blk, 0, stream>>>(w_k, wk_bf, n4w);
  k_convert<<<dim3(1024), blk, 0, stream>>>(w_v, wv_bf, n4w);
  k_convert<<<dim3(1024), blk, 0, stream>>>(w_o, wo_bf, n4w);
  k_maskpack<<<dim3(2048), blk, 0, stream>>>(msk, mpk, 2 * S_LEN * S_LEN);

  dim3 gg(32, 8);
  k_convert<<<dim3(2048), blk, 0, stream>>>(q, x_bf, n4x);
  k_gemm<0><<<gg, blk, 0, stream>>>(x_bf, wq_bf, b_q, Qb);
  k_convert<<<dim3(2048), blk, 0, stream>>>(k, x_bf, n4x);
  k_gemm<0><<<gg, blk, 0, stream>>>(x_bf, wk_bf, b_k, Kb);
  k_convert<<<dim3(2048), blk, 0, stream>>>(v, x_bf, n4x);
  k_gemm<1><<<gg, blk, 0, stream>>>(x_bf, wv_bf, b_v, Vtb);

  k_attn<<<dim3(16, NH, 2), blk, 0, stream>>>(Qb, Kb, Vtb, pb, mpk, x_bf);
  k_gemm<2><<<gg, blk, 0, stream>>>(x_bf, wo_bf, b_o, out);
}

// Round 10
// 278.077 us; speedup vs baseline: 2.2696x; 2.2696x over previous
//
#include <hip/hip_runtime.h>
#include <hip/hip_bf16.h>

#define S_LEN 2048
#define DM 1024
#define NH 16
#define DH 64
#define MTOK 4096

typedef __attribute__((ext_vector_type(8))) __bf16 bf16x8;
typedef __attribute__((ext_vector_type(4))) float f32x4;
typedef unsigned short u16;
typedef unsigned long long u64;

__device__ __forceinline__ u16 f2bf(float f) {
  union { float f; unsigned u; } a; a.f = f;
  unsigned u = a.u;
  u += 0x7fffu + ((u >> 16) & 1u);   // RNE
  return (u16)(u >> 16);
}

__device__ __forceinline__ bf16x8 ld_bf8(const u16* p) {
  return *reinterpret_cast<const bf16x8*>(p);
}

// ---------------- fp32 -> bf16 convert ----------------
__global__ void k_convert(const float* __restrict__ src, u16* __restrict__ dst, int n4) {
  int i = blockIdx.x * blockDim.x + threadIdx.x;
  int stride = gridDim.x * blockDim.x;
  for (; i < n4; i += stride) {
    float4 v = reinterpret_cast<const float4*>(src)[i];
    ushort4 o;
    o.x = f2bf(v.x); o.y = f2bf(v.y); o.z = f2bf(v.z); o.w = f2bf(v.w);
    reinterpret_cast<ushort4*>(dst)[i] = o;
  }
}

// ---------------- mask bit-pack: [B][S][S] i32 -> [B][S][S/64] u64 ----------------
__global__ void k_maskpack(const int* __restrict__ m, u64* __restrict__ o, int n) {
  int i = blockIdx.x * blockDim.x + threadIdx.x;
  int stride = gridDim.x * blockDim.x;
  for (; i < n; i += stride) {
    u64 bal = __ballot(m[i] != 0);
    if ((i & 63) == 0) o[i >> 6] = bal;
  }
}

// ---------------- bf16 GEMM, B^T weights: C = A @ W^T + bias ----------------
template<int MODE>
__global__ __launch_bounds__(256) void k_gemm(
    const u16* __restrict__ A, const u16* __restrict__ Bw,
    const float* __restrict__ bias, void* __restrict__ dst) {
  constexpr int K = DM;
  __shared__ u16 As[128 * 32];
  __shared__ u16 Bs[128 * 32];
  const int tid = threadIdx.x;
  const int lane = tid & 63;
  const int wid = tid >> 6;
  const int wm = wid >> 1, wn = wid & 1;
  const int bm = blockIdx.x * 128;
  const int bn = blockIdx.y * 128;
  const int r0 = tid >> 2;
  const int c0 = (tid & 3) * 8;
  const int fr = lane & 15;
  const int fk = (lane >> 4) * 8;

  f32x4 acc[4][4] = {};

  const u16* ga = A + (size_t)(bm + r0) * K + c0;
  const u16* gb = Bw + (size_t)(bn + r0) * K + c0;

  for (int kt = 0; kt < K; kt += 32) {
    __syncthreads();
    __builtin_amdgcn_global_load_lds(
        (const __attribute__((address_space(1))) void*)(ga + kt),
        (__attribute__((address_space(3))) void*)(&As[r0 * 32 + c0]), 16, 0, 0);
    __builtin_amdgcn_global_load_lds(
        (const __attribute__((address_space(1))) void*)(ga + (size_t)64 * K + kt),
        (__attribute__((address_space(3))) void*)(&As[(r0 + 64) * 32 + c0]), 16, 0, 0);
    __builtin_amdgcn_global_load_lds(
        (const __attribute__((address_space(1))) void*)(gb + kt),
        (__attribute__((address_space(3))) void*)(&Bs[r0 * 32 + c0]), 16, 0, 0);
    __builtin_amdgcn_global_load_lds(
        (const __attribute__((address_space(1))) void*)(gb + (size_t)64 * K + kt),
        (__attribute__((address_space(3))) void*)(&Bs[(r0 + 64) * 32 + c0]), 16, 0, 0);
    __syncthreads();
    bf16x8 af[4], bfr[4];
#pragma unroll
    for (int m = 0; m < 4; ++m) af[m] = ld_bf8(&As[(wm * 64 + m * 16 + fr) * 32 + fk]);
#pragma unroll
    for (int n = 0; n < 4; ++n) bfr[n] = ld_bf8(&Bs[(wn * 64 + n * 16 + fr) * 32 + fk]);
#pragma unroll
    for (int m = 0; m < 4; ++m)
#pragma unroll
      for (int n = 0; n < 4; ++n)
        acc[m][n] = __builtin_amdgcn_mfma_f32_16x16x32_bf16(af[m], bfr[n], acc[m][n], 0, 0, 0);
  }

  const int cr = (lane >> 4) * 4;
  const int cc = lane & 15;
#pragma unroll
  for (int m = 0; m < 4; ++m) {
#pragma unroll
    for (int n = 0; n < 4; ++n) {
      const int colg = bn + wn * 64 + n * 16 + cc;
      const float bv = bias[colg];
      const int rbase = bm + wm * 64 + m * 16 + cr;
      if (MODE == 2) {
        float* o = (float*)dst;
#pragma unroll
        for (int r = 0; r < 4; ++r)
          o[(size_t)(rbase + r) * DM + colg] = acc[m][n][r] + bv;
      } else if (MODE == 0) {
        u16* o = (u16*)dst;
        const int h = colg >> 6, d = colg & 63;
#pragma unroll
        for (int r = 0; r < 4; ++r) {
          const int tok = rbase + r;
          const int b = tok >> 11, s = tok & 2047;
          o[(((size_t)(b * NH + h) * S_LEN) + s) * DH + d] = f2bf(acc[m][n][r] + bv);
        }
      } else {
        u16* o = (u16*)dst;
        const int h = colg >> 6, d = colg & 63;
        const int tok = rbase;
        const int b = tok >> 11, s = tok & 2047;
        ushort4 pk;
        pk.x = f2bf(acc[m][n][0] + bv);
        pk.y = f2bf(acc[m][n][1] + bv);
        pk.z = f2bf(acc[m][n][2] + bv);
        pk.w = f2bf(acc[m][n][3] + bv);
        *reinterpret_cast<ushort4*>(&o[(((size_t)(b * NH + h) * DH) + d) * S_LEN + s]) = pk;
      }
    }
  }
}

// ---------------- fused flash attention, 16q/wave for 4 waves/SIMD ----------------
// Block = 4 waves x 16 q = 64 q, ONE (h, b); grid (32, 16, 2) = 1024 blocks
// = 4 blocks/CU = 4 waves/SIMD. LDS 32 KB (dbuf K,V 64x64 tiles, XOR-swizzled
// via pre-swizzled gload_lds source). Swapped 16x16x32 QK^T (R5-verified):
// lane holds q=lane&15, k = nb*16 + lg*4 + r -> softmax in-lane + 2 shfl.
// P packs in-lane into PV A-frags (no cross-lane); PV pairs two 16-k blocks
// per MFMA with matched k-permutation on the V B-frag (order-agnostic sum).
// Register-frugal: single-stage bias, no prefetch (TLP covers latency).
__global__ __launch_bounds__(256, 4) void k_attn(
    const u16* __restrict__ Qb, const u16* __restrict__ Kb, const u16* __restrict__ Vt,
    const float* __restrict__ bias, const u64* __restrict__ mpk,
    u16* __restrict__ ctx) {
  __shared__ u16 lds[2][2][4096];   // [buf][K, V][64*64]
  const int tid = threadIdx.x;
  const int lane = tid & 63;
  const int w = tid >> 6;
  const int b = blockIdx.z;
  const int h = blockIdx.y;
  const int q0 = blockIdx.x * 64 + w * 16;
  const int lq = lane & 15;
  const int lg = lane >> 4;

  const float* bp = bias + (size_t)h * S_LEN * S_LEN;
  const u16* Kp = Kb + (size_t)(b * NH + h) * S_LEN * DH;
  const u16* Vp = Vt + (size_t)(b * NH + h) * DH * S_LEN;

  // Q as B-fragment: col=q=lane&15, k-elem d = half*32 + lg*8 + j
  bf16x8 qf[2];
  f32x4 cacc[4] = {};
  float m_run = -1e30f, l_run = 0.f;
  {
    const u16* Qp = Qb + (size_t)(b * NH + h) * S_LEN * DH;
    qf[0] = ld_bf8(&Qp[(size_t)(q0 + lq) * DH + lg * 8]);
    qf[1] = ld_bf8(&Qp[(size_t)(q0 + lq) * DH + 32 + lg * 8]);
  }

#define STAGE(ktv, cb) {                                                          \
    _Pragma("unroll") for (int i = 0; i < 2; ++i) {                               \
      const int el = (i * 256 + tid) * 8;                                         \
      const int rr = el >> 6;                                                     \
      const int ce = ((tid & 7) * 8) ^ ((rr & 7) << 3);                           \
      const u16* ksrc = Kp + (size_t)((ktv) + rr) * DH + ce;                      \
      const u16* vsrc = Vp + (size_t)rr * S_LEN + (ktv) + ce;                     \
      __builtin_amdgcn_global_load_lds(                                           \
          (const __attribute__((address_space(1))) void*)ksrc,                    \
          (__attribute__((address_space(3))) void*)&lds[cb][0][el], 16, 0, 0);    \
      __builtin_amdgcn_global_load_lds(                                           \
          (const __attribute__((address_space(1))) void*)vsrc,                    \
          (__attribute__((address_space(3))) void*)&lds[cb][1][el], 16, 0, 0);    \
    } }

// swizzled element offset inside a 64x64 tile (col granularity preserved mod 8)
#define SWZ(row, col) ((row) * 64 + (((((col) >> 3) ^ ((row) & 7)) << 3) | ((col) & 7)))

  STAGE(0, 0);
  int c = 0;
  for (int t = 0; t < S_LEN / 64; ++t) {
    const int ktv = t * 64;
    __syncthreads();                 // own-wave vmcnt(0) + barrier: buf c ready
    if (t + 1 < S_LEN / 64) STAGE(ktv + 64, c ^ 1);

    // ---- bias (4x float4) + mask (1x u64), issued before QK^T consumes ----
    float4 bv[4];
#pragma unroll
    for (int nb = 0; nb < 4; ++nb)
      bv[nb] = *reinterpret_cast<const float4*>(
          &bp[(size_t)(q0 + lq) * S_LEN + ktv + nb * 16 + lg * 4]);
    const u64 mw = mpk[((size_t)(b * S_LEN + q0 + lq)) * 32 + t];

    // ---- S^T = K Q^T : A = K rows (k), B = Q cols (q) ----
    f32x4 sc[4];
    __builtin_amdgcn_s_setprio(1);
#pragma unroll
    for (int nb = 0; nb < 4; ++nb) {
      bf16x8 kf0 = ld_bf8(&lds[c][0][SWZ(nb * 16 + lq, lg * 8)]);
      bf16x8 kf1 = ld_bf8(&lds[c][0][SWZ(nb * 16 + lq, 32 + lg * 8)]);
      f32x4 z = {};
      z = __builtin_amdgcn_mfma_f32_16x16x32_bf16(kf0, qf[0], z, 0, 0, 0);
      sc[nb] = __builtin_amdgcn_mfma_f32_16x16x32_bf16(kf1, qf[1], z, 0, 0, 0);
    }
    __builtin_amdgcn_s_setprio(0);

    // ---- scale + bias + mask (k = nb*16 + lg*4 + r) ----
#pragma unroll
    for (int nb = 0; nb < 4; ++nb)
#pragma unroll
      for (int r = 0; r < 4; ++r) {
        const int shift = nb * 16 + lg * 4 + r;
        const float val = sc[nb][r] * 0.125f + ((const float*)&bv[nb])[r];
        sc[nb][r] = ((mw >> shift) & 1) ? val : -1e9f;
      }
    // ---- max: in-lane tree + xor16 + xor32 ----
    float v0 = fmaxf(fmaxf(sc[0][0], sc[0][1]), fmaxf(sc[0][2], sc[0][3]));
    float v1 = fmaxf(fmaxf(sc[1][0], sc[1][1]), fmaxf(sc[1][2], sc[1][3]));
    float v2 = fmaxf(fmaxf(sc[2][0], sc[2][1]), fmaxf(sc[2][2], sc[2][3]));
    float v3 = fmaxf(fmaxf(sc[3][0], sc[3][1]), fmaxf(sc[3][2], sc[3][3]));
    float vm = fmaxf(fmaxf(v0, v1), fmaxf(v2, v3));
    vm = fmaxf(vm, __shfl_xor(vm, 16));
    vm = fmaxf(vm, __shfl_xor(vm, 32));
    if (!__all(vm <= m_run)) {
      const float mn = fmaxf(m_run, vm);
      const float corr = __expf(m_run - mn);
      m_run = mn;
      l_run *= corr;
      float cr_[4];
#pragma unroll
      for (int r = 0; r < 4; ++r) cr_[r] = __shfl(corr, lg * 4 + r);
#pragma unroll
      for (int nd = 0; nd < 4; ++nd)
#pragma unroll
        for (int r = 0; r < 4; ++r) cacc[nd][r] *= cr_[r];
    }
    // ---- exp + sum ----
    float s0 = 0.f;
#pragma unroll
    for (int nb = 0; nb < 4; ++nb)
#pragma unroll
      for (int r = 0; r < 4; ++r) {
        const float p = __expf(sc[nb][r] - m_run);
        sc[nb][r] = p;
        s0 += p;
      }
    s0 += __shfl_xor(s0, 16);
    s0 += __shfl_xor(s0, 32);
    l_run += s0;
    // ---- pack P in-lane: pa[p] covers nb=2p (j0..3) and nb=2p+1 (j4..7) ----
    bf16x8 pa[2];
#pragma unroll
    for (int p = 0; p < 2; ++p) {
      union { unsigned u[4]; bf16x8 v; } pu;
      pu.u[0] = (unsigned)f2bf(sc[2 * p][0]) | ((unsigned)f2bf(sc[2 * p][1]) << 16);
      pu.u[1] = (unsigned)f2bf(sc[2 * p][2]) | ((unsigned)f2bf(sc[2 * p][3]) << 16);
      pu.u[2] = (unsigned)f2bf(sc[2 * p + 1][0]) | ((unsigned)f2bf(sc[2 * p + 1][1]) << 16);
      pu.u[3] = (unsigned)f2bf(sc[2 * p + 1][2]) | ((unsigned)f2bf(sc[2 * p + 1][3]) << 16);
      pa[p] = pu.v;
    }
    // ---- ctx += P V : B-frag matches pa's k-permutation (two 8B LDS reads) ----
    __builtin_amdgcn_s_setprio(1);
#pragma unroll
    for (int nd = 0; nd < 4; ++nd) {
#pragma unroll
      for (int p = 0; p < 2; ++p) {
        union { unsigned u[4]; bf16x8 v; } vu;
        const unsigned* vp0 = reinterpret_cast<const unsigned*>(
            &lds[c][1][SWZ(nd * 16 + lq, (2 * p) * 16 + lg * 4)]);
        const unsigned* vp1 = reinterpret_cast<const unsigned*>(
            &lds[c][1][SWZ(nd * 16 + lq, (2 * p + 1) * 16 + lg * 4)]);
        vu.u[0] = vp0[0]; vu.u[1] = vp0[1];
        vu.u[2] = vp1[0]; vu.u[3] = vp1[1];
        cacc[nd] = __builtin_amdgcn_mfma_f32_16x16x32_bf16(pa[p], vu.v, cacc[nd], 0, 0, 0);
      }
    }
    __builtin_amdgcn_s_setprio(0);
    c ^= 1;
  }
#undef STAGE
#undef SWZ

  // ---- epilogue: cacc row q = lg*4+r, col d = nd*16+lq ----
#pragma unroll
  for (int r = 0; r < 4; ++r) {
    const float linv = 1.0f / __shfl(l_run, lg * 4 + r);
    const int tok = b * S_LEN + q0 + lg * 4 + r;
    u16* cp = ctx + (size_t)tok * DM + h * DH;
#pragma unroll
    for (int nd = 0; nd < 4; ++nd)
      cp[nd * 16 + lq] = f2bf(cacc[nd][r] * linv);
  }
}

extern "C" void kernel_launch(void* const* d_in, const int* in_sizes, int n_in,
                              void* d_out, int out_size, void* d_ws, size_t ws_size,
                              hipStream_t stream) {
  const float* q   = (const float*)d_in[0];
  const float* k   = (const float*)d_in[1];
  const float* v   = (const float*)d_in[2];
  const int*   msk = (const int*)d_in[3];
  const float* pb  = (const float*)d_in[4];
  const float* w_q = (const float*)d_in[5];
  const float* b_q = (const float*)d_in[6];
  const float* w_k = (const float*)d_in[7];
  const float* b_k = (const float*)d_in[8];
  const float* w_v = (const float*)d_in[9];
  const float* b_v = (const float*)d_in[10];
  const float* w_o = (const float*)d_in[11];
  const float* b_o = (const float*)d_in[12];
  float* out = (float*)d_out;

  char* ws = (char*)d_ws;
  u16* wq_bf = (u16*)(ws + ((size_t)0 << 20));
  u16* wk_bf = (u16*)(ws + ((size_t)2 << 20));
  u16* wv_bf = (u16*)(ws + ((size_t)4 << 20));
  u16* wo_bf = (u16*)(ws + ((size_t)6 << 20));
  u16* x_bf  = (u16*)(ws + ((size_t)8 << 20));   // staging; reused as ctx
  u16* Qb    = (u16*)(ws + ((size_t)16 << 20));
  u16* Kb    = (u16*)(ws + ((size_t)24 << 20));
  u16* Vtb   = (u16*)(ws + ((size_t)32 << 20));
  u64* mpk   = (u64*)(ws + ((size_t)40 << 20));  // 1 MB packed mask

  dim3 blk(256);
  const int n4w = DM * DM / 4;
  const int n4x = MTOK * DM / 4;
  k_convert<<<dim3(1024), blk, 0, stream>>>(w_q, wq_bf, n4w);
  k_convert<<<dim3(1024), blk, 0, stream>>>(w_k, wk_bf, n4w);
  k_convert<<<dim3(1024), blk, 0, stream>>>(w_v, wv_bf, n4w);
  k_convert<<<dim3(1024), blk, 0, stream>>>(w_o, wo_bf, n4w);
  k_maskpack<<<dim3(2048), blk, 0, stream>>>(msk, mpk, 2 * S_LEN * S_LEN);

  dim3 gg(32, 8);
  k_convert<<<dim3(2048), blk, 0, stream>>>(q, x_bf, n4x);
  k_gemm<0><<<gg, blk, 0, stream>>>(x_bf, wq_bf, b_q, Qb);
  k_convert<<<dim3(2048), blk, 0, stream>>>(k, x_bf, n4x);
  k_gemm<0><<<gg, blk, 0, stream>>>(x_bf, wk_bf, b_k, Kb);
  k_convert<<<dim3(2048), blk, 0, stream>>>(v, x_bf, n4x);
  k_gemm<1><<<gg, blk, 0, stream>>>(x_bf, wv_bf, b_v, Vtb);

  k_attn<<<dim3(32, NH, 2), blk, 0, stream>>>(Qb, Kb, Vtb, pb, mpk, x_bf);
  k_gemm<2><<<gg, blk, 0, stream>>>(x_bf, wo_bf, b_o, out);
}